// Round 13
// baseline (113.957 us; speedup 1.0000x reference)
//
#include <hip/hip_runtime.h>
#include <hip/hip_bf16.h>
#include <math.h>

#define BB 2
#define NN 16384
#define KK 16
#define CC 128
#define COUT 128
#define NODES (BB * NN)
#define SP 136   // bf16 staging row pitch (elements; 272 B -> 16B-aligned rows)
#define SQP 136  // fp8 staging row pitch (bytes)
#define ZP 136   // z-tile row pitch (elements)
#define NPW 8    // nodes per wave
#define NPB 32   // nodes per block (4 waves x 8)
#define XBLK 2048

typedef __attribute__((ext_vector_type(8))) short bf16x8;
typedef __attribute__((ext_vector_type(4))) float f32x4;
typedef __attribute__((ext_vector_type(2))) float f32x2;  // matches fp8 builtin returns

__device__ __forceinline__ bf16x8 cvt8(f32x4 a, f32x4 b) {
    union { bf16x8 v; __hip_bfloat162 h[4]; } u;
    u.h[0] = __float22bfloat162_rn(make_float2(a[0], a[1]));
    u.h[1] = __float22bfloat162_rn(make_float2(a[2], a[3]));
    u.h[2] = __float22bfloat162_rn(make_float2(b[0], b[1]));
    u.h[3] = __float22bfloat162_rn(make_float2(b[2], b[3]));
    return u.v;
}

// fp8x8 (int2) -> bf16x8
__device__ __forceinline__ bf16x8 up8(int2 wb) {
    f32x2 f0 = __builtin_amdgcn_cvt_pk_f32_fp8(wb.x, false);
    f32x2 f1 = __builtin_amdgcn_cvt_pk_f32_fp8(wb.x, true);
    f32x2 f2 = __builtin_amdgcn_cvt_pk_f32_fp8(wb.y, false);
    f32x2 f3 = __builtin_amdgcn_cvt_pk_f32_fp8(wb.y, true);
    union { bf16x8 v; __hip_bfloat162 h[4]; } u;
    u.h[0] = __float22bfloat162_rn(make_float2(f0[0], f0[1]));
    u.h[1] = __float22bfloat162_rn(make_float2(f1[0], f1[1]));
    u.h[2] = __float22bfloat162_rn(make_float2(f2[0], f2[1]));
    u.h[3] = __float22bfloat162_rn(make_float2(f3[0], f3[1]));
    return u.v;
}

// DPP row_ror adds within each 16-lane row (VALU pipe).
template <int CTRL>
__device__ __forceinline__ float rot_add(float v) {
    int r = __builtin_amdgcn_update_dpp(0, __float_as_int(v), CTRL, 0xF, 0xF, true);
    return v + __int_as_float(r);
}
__device__ __forceinline__ float row16_sum(float v) {
    v = rot_add<0x128>(v); v = rot_add<0x124>(v);
    v = rot_add<0x122>(v); v = rot_add<0x121>(v);
    return v;
}

// ---------------------------------------------------------------------------
// Kernel P: x (fp32) -> xh (bf16) + xq (fp8 e4m3), streaming. 8 elems/thread.
// Tail blocks cast W fp32 -> wh bf16 (same cvt8 rounding as before).
// ---------------------------------------------------------------------------
__global__ __launch_bounds__(256) void cast_x(
    const float* __restrict__ x,
    __hip_bfloat16* __restrict__ xh,
    unsigned char* __restrict__ xq,
    const float* __restrict__ W,
    __hip_bfloat16* __restrict__ wh)
{
    const int bid = blockIdx.x;
    if (bid >= XBLK) {
        const int i = (bid - XBLK) * 256 + threadIdx.x;
        const f32x4* p = (const f32x4*)(W + (size_t)i * 8);
        f32x4 a = p[0];
        f32x4 b = p[1];
        *(bf16x8*)(wh + (size_t)i * 8) = cvt8(a, b);
        return;
    }
    const int i = bid * 256 + threadIdx.x;
    const f32x4* p = (const f32x4*)(x + (size_t)i * 8);
    f32x4 a = __builtin_nontemporal_load(p);
    f32x4 b = __builtin_nontemporal_load(p + 1);
    *(bf16x8*)(xh + (size_t)i * 8) = cvt8(a, b);
    int lo = __builtin_amdgcn_cvt_pk_fp8_f32(a[0], a[1], 0, false);
    lo     = __builtin_amdgcn_cvt_pk_fp8_f32(a[2], a[3], lo, true);
    int hi = __builtin_amdgcn_cvt_pk_fp8_f32(b[0], b[1], 0, false);
    hi     = __builtin_amdgcn_cvt_pk_fp8_f32(b[2], b[3], hi, true);
    int2 v; v.x = lo; v.y = hi;
    *(int2*)(xq + (size_t)i * 8) = v;
}

// Softmax column-sum: scores (C-layout) -> w for this lane's Xj row m.
__device__ __forceinline__ float col_weight(f32x4 acc) {
    const float scale = 0.08838834764831843f;  // 1/sqrt(128)
    float w = 0.f;
    #pragma unroll
    for (int i = 0; i < 4; ++i) {
        float e = __expf(acc[i] * scale);
        float s = row16_sum(e);
        w += e * __builtin_amdgcn_rcpf(s);
    }
    w += __shfl_xor(w, 16, 64);
    w += __shfl_xor(w, 32, 64);
    return w;
}

struct Rows { int2 qi[4]; bf16x8 j[4]; };

// Staged-gather shape (R0-proven): Xi fp8 4 inst x (4 rows x 128B),
// Xj bf16 4 inst x (4 rows x 256B) — few LONG segments per instruction.
// Edge indices pre-hoisted in m-layout regs; redistributed via __shfl.
__device__ __forceinline__ void gather_rows(
    int ejv, int eiv, int r, int c,
    const __hip_bfloat16* __restrict__ xbh,
    const unsigned char* __restrict__ xbq,
    Rows& g)
{
    #pragma unroll
    for (int gg = 0; gg < 4; ++gg) {
        int ri = __shfl(eiv, gg * 4 + r, 16);
        g.qi[gg] = *(const int2*)(xbq + (size_t)ri * CC + c * 8);
    }
    #pragma unroll
    for (int gg = 0; gg < 4; ++gg) {
        int rj = __shfl(ejv, gg * 4 + r, 16);
        g.j[gg] = *(const bf16x8*)(xbh + (size_t)rj * CC + c * 8);
    }
}

// ---------------------------------------------------------------------------
// Fused kernel, LONG-CHAIN variant: block = 32 nodes as 4 waves x 8 nodes
// (R12 measured the dose-response backwards: 2 bodies/wave=105.9,
// 4=102.9 — one uncovered startup stall per wave amortizes over the chain,
// so MORE bodies/wave is the winning direction). Depth-2 peeling generalizes
// to 8 bodies: gather(n+2) before body(n), 3 live 24-reg buffers at steady
// state. Register guards vs the 128-VGPR line (R7): edges+rx hoisted in TWO
// batches (4..7 issued after body0, still OLDER than gather4 -> R9's
// oldest-first invariant holds: staging's wait on gather(n) retires rx(n)
// free), and the w-broadcast readback chunked f32x4-at-a-time (peak 4 regs
// vs 16; same j%4 accumulator grouping -> bit-identical sums).
// Grid 1024 blocks = exactly one resident set (4 blk/CU: LDS 34816 B) ->
// no second dispatch round convoy. Linear: each wave 2 M-tiles x 2 ct.
// Canary: attn_fused in rocprof top-5 = spill (revert to R8).
// ---------------------------------------------------------------------------
__global__ __launch_bounds__(256, 4) void attn_fused(
    const __hip_bfloat16* __restrict__ xh,
    const unsigned char* __restrict__ xq,
    const int* __restrict__ edge,
    const __hip_bfloat16* __restrict__ wh,
    const float* __restrict__ bias,
    float* __restrict__ out)
{
    __shared__ alignas(16) __hip_bfloat16 stgj[4][16 * SP];  // Xj bf16: 17408 B
    __shared__ alignas(16) unsigned char stgq[4][16 * SQP];  // Xi fp8:  8704 B
    __shared__ alignas(16) __hip_bfloat16 zt[NPB][ZP];       // z tile:  8704 B

    const int t = threadIdx.x;
    const int wv = t >> 6;
    const int lane = t & 63;
    const int m = lane & 15;   // fragment row
    const int q = lane >> 4;   // fragment k-quad
    const int r = lane >> 4;   // staging: row-in-group 0..3
    const int c = lane & 15;   // staging: chunk within row
    const int base = blockIdx.x * NPB;
    const int node0 = base + wv * NPW;
    const int b = node0 >> 14;          // block of 32 nodes never straddles NN

    const __hip_bfloat16* xbh = xh + (size_t)b * (size_t)(NN * CC);
    const unsigned char*  xbq = xq + (size_t)b * (size_t)(NN * CC);
    __hip_bfloat16* sj = &stgj[wv][0];
    unsigned char*  sq = &stgq[wv][0];
    float*          wb16 = (float*)sq;  // 64B w-broadcast corner (aliased)

    int ejv[NPW], eiv[NPW];
    __hip_bfloat162 rxv[NPW];

    // ---- hoist batch 1: edges + residuals for nodes 0..3 (oldest loads) ----
    #pragma unroll
    for (int n = 0; n < 4; ++n) {
        const int* ej = edge + (size_t)(node0 + n) * KK;
        ejv[n] = __builtin_nontemporal_load(ej + m);
        eiv[n] = __builtin_nontemporal_load(ej + (size_t)NODES * KK + m);
        const int nloc = (node0 + n) & (NN - 1);
        rxv[n] = *(const __hip_bfloat162*)(xbh + (size_t)nloc * CC + 2 * lane);
    }

    // Per-node body: stage -> scores -> softmax -> column-reduce h -> zt row.
    auto body = [&](const Rows& A, __hip_bfloat162 rx, int it) {
        // ---- stage node `it` to LDS (wave-private; in-order DS).
        //      The implicit wait here is on A's gathers; rx/edges for this
        //      node are OLDER, so they retire with it — no extra drain. ----
        #pragma unroll
        for (int g = 0; g < 4; ++g)
            *(int2*)(sq + (g * 4 + r) * SQP + c * 8) = A.qi[g];
        #pragma unroll
        for (int g = 0; g < 4; ++g)
            *(bf16x8*)(sj + (g * 4 + r) * SP + c * 8) = A.j[g];

        // ---- fragments + scores; Xi fp8->bf16 fused into MFMA loop ----
        f32x4 acc = {0.f, 0.f, 0.f, 0.f};
        #pragma unroll
        for (int s = 0; s < 4; ++s) {
            int2 wa = *(const int2*)(sq + m * SQP + s * 32 + q * 8);
            bf16x8 bfr = *(const bf16x8*)(sj + m * SP + s * 32 + q * 8);
            acc = __builtin_amdgcn_mfma_f32_16x16x32_bf16(up8(wa), bfr, acc, 0, 0, 0);
        }

        // ---- softmax col-sum: wj for j = lane&15, replicated over q ----
        const float wj = col_weight(acc);

        // ---- h via column reduction: broadcast w, then each lane fmas its
        //      own 2 channels from Xj columns. w read back CHUNKED (one
        //      f32x4 live at a time, peak 4 regs vs 16); j%4 accumulator
        //      grouping identical to the unchunked version -> bit-identical.
        if (lane < 16) wb16[lane] = wj;
        float ax[4] = {0.f, 0.f, 0.f, 0.f};
        float ay[4] = {0.f, 0.f, 0.f, 0.f};
        const char* sjb = (const char*)sj + 4 * lane;
        #pragma unroll
        for (int jq = 0; jq < 4; ++jq) {
            f32x4 wq = *(const f32x4*)&wb16[4 * jq];
            #pragma unroll
            for (int e = 0; e < 4; ++e) {
                const int j = jq * 4 + e;
                unsigned u = *(const unsigned*)(sjb + j * (SP * 2));
                float lo = __uint_as_float(u << 16);
                float hi = __uint_as_float(u & 0xffff0000u);
                ax[e] = fmaf(wq[e], lo, ax[e]);
                ay[e] = fmaf(wq[e], hi, ay[e]);
            }
        }
        float hx = (ax[0] + ax[1]) + (ax[2] + ax[3]);
        float hy = (ay[0] + ay[1]) + (ay[2] + ay[3]);

        // ---- residual + cast, into the z LDS tile ----
        float2 xc = __bfloat1622float2(rx);
        const int row = wv * NPW + it;
        *(__hip_bfloat162*)(&zt[row][2 * lane]) =
            __float22bfloat162_rn(make_float2(xc.x + hx, xc.y + hy));
    };

    // ---- depth-2 prefetch over 8 bodies, hand-peeled (pure SSA) ----
    Rows A0, A1, A2, A3, A4, A5, A6, A7;
    gather_rows(ejv[0], eiv[0], r, c, xbh, xbq, A0);
    gather_rows(ejv[1], eiv[1], r, c, xbh, xbq, A1);
    gather_rows(ejv[2], eiv[2], r, c, xbh, xbq, A2);
    body(A0, rxv[0], 0);

    // ---- hoist batch 2: edges + residuals for nodes 4..7 (issued before
    //      gather4..7 -> older than their consumers; values arrive during
    //      bodies 1-2, well before gather4 needs edge4) ----
    #pragma unroll
    for (int n = 4; n < 8; ++n) {
        const int* ej = edge + (size_t)(node0 + n) * KK;
        ejv[n] = __builtin_nontemporal_load(ej + m);
        eiv[n] = __builtin_nontemporal_load(ej + (size_t)NODES * KK + m);
        const int nloc = (node0 + n) & (NN - 1);
        rxv[n] = *(const __hip_bfloat162*)(xbh + (size_t)nloc * CC + 2 * lane);
    }

    gather_rows(ejv[3], eiv[3], r, c, xbh, xbq, A3);
    body(A1, rxv[1], 1);
    gather_rows(ejv[4], eiv[4], r, c, xbh, xbq, A4);
    body(A2, rxv[2], 2);
    gather_rows(ejv[5], eiv[5], r, c, xbh, xbq, A5);
    body(A3, rxv[3], 3);
    gather_rows(ejv[6], eiv[6], r, c, xbh, xbq, A6);
    body(A4, rxv[4], 4);
    gather_rows(ejv[7], eiv[7], r, c, xbh, xbq, A7);
    body(A5, rxv[5], 5);
    body(A6, rxv[6], 6);
    body(A7, rxv[7], 7);

    __syncthreads();

    // ---- fused linear: out[32 nodes][128] = relu(zt @ W^T + b) ----
    #pragma unroll
    for (int mt = 0; mt < 2; ++mt) {
        bf16x8 zfr[4];
        #pragma unroll
        for (int s = 0; s < 4; ++s)
            zfr[s] = *(const bf16x8*)(&zt[mt * 16 + m][s * 32 + q * 8]);

        #pragma unroll
        for (int half = 0; half < 2; ++half) {
            const int ct = wv * 2 + half;            // cout-tile 0..7
            const __hip_bfloat16* wp = wh + (size_t)(ct * 16 + m) * CC + q * 8;
            bf16x8 wfr[4];
            #pragma unroll
            for (int s = 0; s < 4; ++s)
                wfr[s] = *(const bf16x8*)(wp + s * 32);
            const float bv = bias[ct * 16 + m];
            f32x4 acc = {0.f, 0.f, 0.f, 0.f};
            #pragma unroll
            for (int s = 0; s < 4; ++s)
                acc = __builtin_amdgcn_mfma_f32_16x16x32_bf16(zfr[s], wfr[s], acc, 0, 0, 0);
            // C/D layout: col = lane&15 = cout-in-tile, row = q*4+i = node
            float* op = out + (size_t)(base + mt * 16 + q * 4) * COUT + ct * 16 + m;
            #pragma unroll
            for (int i = 0; i < 4; ++i)
                op[(size_t)i * COUT] = fmaxf(acc[i] + bv, 0.f);
        }
    }
}

extern "C" void kernel_launch(void* const* d_in, const int* in_sizes, int n_in,
                              void* d_out, int out_size, void* d_ws, size_t ws_size,
                              hipStream_t stream) {
    const float* x    = (const float*)d_in[0];
    const int*   edge = (const int*)d_in[1];
    const float* W    = (const float*)d_in[2];
    const float* bias = (const float*)d_in[3];
    float* out = (float*)d_out;
    __hip_bfloat16* xh = (__hip_bfloat16*)d_ws;                              // 8 MB
    unsigned char*  xq = (unsigned char*)d_ws + 8 * 1024 * 1024;             // 4 MB
    __hip_bfloat16* wh = (__hip_bfloat16*)((char*)d_ws + 12 * 1024 * 1024);  // 32 KB

    cast_x<<<XBLK + (COUT * CC) / (256 * 8), 256, 0, stream>>>(x, xh, xq, W, wh);
    attn_fused<<<NODES / NPB, 256, 0, stream>>>(xh, xq, edge, wh, bias, out);
}

// Round 14
// 103.259 us; speedup vs baseline: 1.1036x; 1.1036x over previous
//
#include <hip/hip_runtime.h>
#include <hip/hip_bf16.h>
#include <math.h>

#define BB 2
#define NN 16384
#define KK 16
#define CC 128
#define COUT 128
#define NODES (BB * NN)
#define SP 136   // bf16 staging row pitch (elements; 272 B -> 16B-aligned rows)
#define SQP 136  // fp8 staging row pitch (bytes)
#define ZP 136   // z-tile row pitch (elements)
#define XBLK 2048

typedef __attribute__((ext_vector_type(8))) short bf16x8;
typedef __attribute__((ext_vector_type(4))) float f32x4;
typedef __attribute__((ext_vector_type(2))) float f32x2;  // matches fp8 builtin returns

__device__ __forceinline__ bf16x8 cvt8(f32x4 a, f32x4 b) {
    union { bf16x8 v; __hip_bfloat162 h[4]; } u;
    u.h[0] = __float22bfloat162_rn(make_float2(a[0], a[1]));
    u.h[1] = __float22bfloat162_rn(make_float2(a[2], a[3]));
    u.h[2] = __float22bfloat162_rn(make_float2(b[0], b[1]));
    u.h[3] = __float22bfloat162_rn(make_float2(b[2], b[3]));
    return u.v;
}

// fp8x8 (int2) -> bf16x8
__device__ __forceinline__ bf16x8 up8(int2 wb) {
    f32x2 f0 = __builtin_amdgcn_cvt_pk_f32_fp8(wb.x, false);
    f32x2 f1 = __builtin_amdgcn_cvt_pk_f32_fp8(wb.x, true);
    f32x2 f2 = __builtin_amdgcn_cvt_pk_f32_fp8(wb.y, false);
    f32x2 f3 = __builtin_amdgcn_cvt_pk_f32_fp8(wb.y, true);
    union { bf16x8 v; __hip_bfloat162 h[4]; } u;
    u.h[0] = __float22bfloat162_rn(make_float2(f0[0], f0[1]));
    u.h[1] = __float22bfloat162_rn(make_float2(f1[0], f1[1]));
    u.h[2] = __float22bfloat162_rn(make_float2(f2[0], f2[1]));
    u.h[3] = __float22bfloat162_rn(make_float2(f3[0], f3[1]));
    return u.v;
}

// DPP row_ror adds within each 16-lane row (VALU pipe).
template <int CTRL>
__device__ __forceinline__ float rot_add(float v) {
    int r = __builtin_amdgcn_update_dpp(0, __float_as_int(v), CTRL, 0xF, 0xF, true);
    return v + __int_as_float(r);
}
__device__ __forceinline__ float row16_sum(float v) {
    v = rot_add<0x128>(v); v = rot_add<0x124>(v);
    v = rot_add<0x122>(v); v = rot_add<0x121>(v);
    return v;
}

// ---------------------------------------------------------------------------
// Kernel P: x (fp32) -> xh (bf16) + xq (fp8 e4m3), streaming. 8 elems/thread.
// Tail blocks cast W fp32 -> wh bf16 (same cvt8 rounding as before).
// ---------------------------------------------------------------------------
__global__ __launch_bounds__(256) void cast_x(
    const float* __restrict__ x,
    __hip_bfloat16* __restrict__ xh,
    unsigned char* __restrict__ xq,
    const float* __restrict__ W,
    __hip_bfloat16* __restrict__ wh)
{
    const int bid = blockIdx.x;
    if (bid >= XBLK) {
        const int i = (bid - XBLK) * 256 + threadIdx.x;
        const f32x4* p = (const f32x4*)(W + (size_t)i * 8);
        f32x4 a = p[0];
        f32x4 b = p[1];
        *(bf16x8*)(wh + (size_t)i * 8) = cvt8(a, b);
        return;
    }
    const int i = bid * 256 + threadIdx.x;
    const f32x4* p = (const f32x4*)(x + (size_t)i * 8);
    f32x4 a = __builtin_nontemporal_load(p);
    f32x4 b = __builtin_nontemporal_load(p + 1);
    *(bf16x8*)(xh + (size_t)i * 8) = cvt8(a, b);
    int lo = __builtin_amdgcn_cvt_pk_fp8_f32(a[0], a[1], 0, false);
    lo     = __builtin_amdgcn_cvt_pk_fp8_f32(a[2], a[3], lo, true);
    int hi = __builtin_amdgcn_cvt_pk_fp8_f32(b[0], b[1], 0, false);
    hi     = __builtin_amdgcn_cvt_pk_fp8_f32(b[2], b[3], hi, true);
    int2 v; v.x = lo; v.y = hi;
    *(int2*)(xq + (size_t)i * 8) = v;
}

// Softmax column-sum: scores (C-layout) -> w for this lane's Xj row m.
__device__ __forceinline__ float col_weight(f32x4 acc) {
    const float scale = 0.08838834764831843f;  // 1/sqrt(128)
    float w = 0.f;
    #pragma unroll
    for (int i = 0; i < 4; ++i) {
        float e = __expf(acc[i] * scale);
        float s = row16_sum(e);
        w += e * __builtin_amdgcn_rcpf(s);
    }
    w += __shfl_xor(w, 16, 64);
    w += __shfl_xor(w, 32, 64);
    return w;
}

struct Rows { int2 qi[4]; bf16x8 j[4]; };

// Staged-gather shape (R0-proven): Xi fp8 4 inst x (4 rows x 128B),
// Xj bf16 4 inst x (4 rows x 256B) — few LONG segments per instruction
// (R1's fragment-order gathers regressed 11.5us: TA/transaction-bound path).
// Edge indices pre-hoisted in m-layout regs; redistributed via __shfl.
__device__ __forceinline__ void gather_rows(
    int ejv, int eiv, int r, int c,
    const __hip_bfloat16* __restrict__ xbh,
    const unsigned char* __restrict__ xbq,
    Rows& g)
{
    #pragma unroll
    for (int gg = 0; gg < 4; ++gg) {
        int ri = __shfl(eiv, gg * 4 + r, 16);
        g.qi[gg] = *(const int2*)(xbq + (size_t)ri * CC + c * 8);
    }
    #pragma unroll
    for (int gg = 0; gg < 4; ++gg) {
        int rj = __shfl(ejv, gg * 4 + r, 16);
        g.j[gg] = *(const bf16x8*)(xbh + (size_t)rj * CC + c * 8);
    }
}

// ---------------------------------------------------------------------------
// Fused kernel — LOCKED-IN R8 OPTIMUM (102.9us, session best). Block = 16
// nodes as 4 waves x 4 bodies (the measured chain-length optimum:
// 2 bodies=105.9, 4=102.9, 8=114.0 — startup-stall amortization vs register
// state). Depth-2 prefetch hand-peeled with distinct A,B,C0,C1 buffers
// (pure SSA; depth>=3 spills past the 128-VGPR step, R7). Edge indices +
// residual rows hoisted FIRST (oldest loads: their consumption never drains
// the prefetch pipe — consuming a late-issued load costs vmcnt(0) = full
// drain, R9's +8.4us). __expf (exp2f was noise-negative, R10).
// __launch_bounds__(256,4) = the 128-VGPR allocator step ((256,5) caps at
// 48 and spills, R7). LDS 30464 B. Linear fused: no z round-trip.
// Canary: attn_fused in rocprof top-5 = spill/drain.
// ---------------------------------------------------------------------------
__global__ __launch_bounds__(256, 4) void attn_fused(
    const __hip_bfloat16* __restrict__ xh,
    const unsigned char* __restrict__ xq,
    const int* __restrict__ edge,
    const __hip_bfloat16* __restrict__ wh,
    const float* __restrict__ bias,
    float* __restrict__ out)
{
    __shared__ alignas(16) __hip_bfloat16 stgj[4][16 * SP];  // Xj bf16
    __shared__ alignas(16) unsigned char stgq[4][16 * SQP];  // Xi fp8 (+w corner)
    __shared__ alignas(16) __hip_bfloat16 zt[16][ZP];        // z tile

    const int t = threadIdx.x;
    const int wv = t >> 6;
    const int lane = t & 63;
    const int m = lane & 15;   // fragment row
    const int q = lane >> 4;   // fragment k-quad
    const int r = lane >> 4;   // staging: row-in-group 0..3
    const int c = lane & 15;   // staging: chunk within row
    const int base = blockIdx.x * 16;
    const int node0 = base + wv * 4;
    const int b = node0 >> 14;          // block of 16 nodes never straddles NN

    const __hip_bfloat16* xbh = xh + (size_t)b * (size_t)(NN * CC);
    const unsigned char*  xbq = xq + (size_t)b * (size_t)(NN * CC);
    __hip_bfloat16* sj = &stgj[wv][0];
    unsigned char*  sq = &stgq[wv][0];
    float*          wb16 = (float*)sq;  // 64B w-broadcast corner (aliased)

    // ---- hoisted edge indices (m-layout) + residual rows for all 4 nodes.
    //      Issued BEFORE all gathers (oldest-first invariant). ----
    int ejv[4], eiv[4];
    __hip_bfloat162 rxv[4];
    #pragma unroll
    for (int n = 0; n < 4; ++n) {
        const int* ej = edge + (size_t)(node0 + n) * KK;
        ejv[n] = __builtin_nontemporal_load(ej + m);
        eiv[n] = __builtin_nontemporal_load(ej + (size_t)NODES * KK + m);
        const int nloc = (node0 + n) & (NN - 1);
        rxv[n] = *(const __hip_bfloat162*)(xbh + (size_t)nloc * CC + 2 * lane);
    }

    // Per-node body: stage -> scores -> softmax -> column-reduce h -> zt row.
    auto body = [&](const Rows& A, int it) {
        // ---- stage node `it` to LDS (wave-private; in-order DS) ----
        #pragma unroll
        for (int g = 0; g < 4; ++g)
            *(int2*)(sq + (g * 4 + r) * SQP + c * 8) = A.qi[g];
        #pragma unroll
        for (int g = 0; g < 4; ++g)
            *(bf16x8*)(sj + (g * 4 + r) * SP + c * 8) = A.j[g];

        // ---- fragments + scores; Xi fp8->bf16 fused into MFMA loop ----
        f32x4 acc = {0.f, 0.f, 0.f, 0.f};
        #pragma unroll
        for (int s = 0; s < 4; ++s) {
            int2 wa = *(const int2*)(sq + m * SQP + s * 32 + q * 8);
            bf16x8 bfr = *(const bf16x8*)(sj + m * SP + s * 32 + q * 8);
            acc = __builtin_amdgcn_mfma_f32_16x16x32_bf16(up8(wa), bfr, acc, 0, 0, 0);
        }

        // ---- softmax col-sum: wj for j = lane&15, replicated over q ----
        const float wj = col_weight(acc);

        // ---- h via column reduction: broadcast w, each lane fmas its own
        //      2 channels from Xj columns (sq consumed; corner aliased) ----
        if (lane < 16) wb16[lane] = wj;
        f32x4 wv0 = *(const f32x4*)&wb16[0];
        f32x4 wv1 = *(const f32x4*)&wb16[4];
        f32x4 wv2 = *(const f32x4*)&wb16[8];
        f32x4 wv3 = *(const f32x4*)&wb16[12];
        float wvv[16] = {wv0[0], wv0[1], wv0[2], wv0[3],
                         wv1[0], wv1[1], wv1[2], wv1[3],
                         wv2[0], wv2[1], wv2[2], wv2[3],
                         wv3[0], wv3[1], wv3[2], wv3[3]};
        float ax[4] = {0.f, 0.f, 0.f, 0.f};
        float ay[4] = {0.f, 0.f, 0.f, 0.f};
        const char* sjb = (const char*)sj + 4 * lane;
        #pragma unroll
        for (int j = 0; j < 16; ++j) {
            unsigned u = *(const unsigned*)(sjb + j * (SP * 2));
            float lo = __uint_as_float(u << 16);
            float hi = __uint_as_float(u & 0xffff0000u);
            ax[j & 3] = fmaf(wvv[j], lo, ax[j & 3]);
            ay[j & 3] = fmaf(wvv[j], hi, ay[j & 3]);
        }
        float hx = (ax[0] + ax[1]) + (ax[2] + ax[3]);
        float hy = (ay[0] + ay[1]) + (ay[2] + ay[3]);

        // ---- residual + cast, into the z LDS tile ----
        float2 xc = __bfloat1622float2(rxv[it]);
        const int row = wv * 4 + it;
        *(__hip_bfloat162*)(&zt[row][2 * lane]) =
            __float22bfloat162_rn(make_float2(xc.x + hx, xc.y + hy));
    };

    // ---- 2-deep prefetch, hand-peeled (distinct buffers, pure SSA) ----
    Rows A, B, C0, C1;
    gather_rows(ejv[0], eiv[0], r, c, xbh, xbq, A);
    gather_rows(ejv[1], eiv[1], r, c, xbh, xbq, B);

    gather_rows(ejv[2], eiv[2], r, c, xbh, xbq, C0);   // issue ahead of A's stage
    body(A, 0);
    gather_rows(ejv[3], eiv[3], r, c, xbh, xbq, C1);   // issue ahead of B's stage
    body(B, 1);
    body(C0, 2);
    body(C1, 3);

    __syncthreads();

    // ---- fused linear: out[16 nodes][128] = relu(zt @ W^T + b) ----
    bf16x8 zfr[4];
    #pragma unroll
    for (int s = 0; s < 4; ++s)
        zfr[s] = *(const bf16x8*)(&zt[m][s * 32 + q * 8]);

    #pragma unroll
    for (int half = 0; half < 2; ++half) {
        const int ct = wv * 2 + half;            // cout-tile 0..7
        const __hip_bfloat16* wp = wh + (size_t)(ct * 16 + m) * CC + q * 8;
        bf16x8 wfr[4];
        #pragma unroll
        for (int s = 0; s < 4; ++s)
            wfr[s] = *(const bf16x8*)(wp + s * 32);
        const float bv = bias[ct * 16 + m];
        f32x4 acc = {0.f, 0.f, 0.f, 0.f};
        #pragma unroll
        for (int s = 0; s < 4; ++s)
            acc = __builtin_amdgcn_mfma_f32_16x16x32_bf16(zfr[s], wfr[s], acc, 0, 0, 0);
        // C/D layout: col = lane&15 = cout-in-tile, row = q*4+i = node-in-tile
        float* op = out + (size_t)(base + q * 4) * COUT + ct * 16 + m;
        #pragma unroll
        for (int i = 0; i < 4; ++i)
            op[(size_t)i * COUT] = fmaxf(acc[i] + bv, 0.f);
    }
}

extern "C" void kernel_launch(void* const* d_in, const int* in_sizes, int n_in,
                              void* d_out, int out_size, void* d_ws, size_t ws_size,
                              hipStream_t stream) {
    const float* x    = (const float*)d_in[0];
    const int*   edge = (const int*)d_in[1];
    const float* W    = (const float*)d_in[2];
    const float* bias = (const float*)d_in[3];
    float* out = (float*)d_out;
    __hip_bfloat16* xh = (__hip_bfloat16*)d_ws;                              // 8 MB
    unsigned char*  xq = (unsigned char*)d_ws + 8 * 1024 * 1024;             // 4 MB
    __hip_bfloat16* wh = (__hip_bfloat16*)((char*)d_ws + 12 * 1024 * 1024);  // 32 KB

    cast_x<<<XBLK + (COUT * CC) / (256 * 8), 256, 0, stream>>>(x, xh, xq, W, wh);
    attn_fused<<<NODES / 16, 256, 0, stream>>>(xh, xq, edge, wh, bias, out);
}